// Round 15
// baseline (367.792 us; speedup 1.0000x reference)
//
#include <hip/hip_runtime.h>
#include <hip/hip_bf16.h>

typedef unsigned short u16;
typedef __attribute__((ext_vector_type(4))) float f32x4;
typedef __attribute__((ext_vector_type(16))) float f32x16;
typedef __attribute__((ext_vector_type(8))) short s16x8;
typedef __attribute__((ext_vector_type(4))) unsigned short u16x4;

static __device__ __forceinline__ u16 f32_to_bf16(float f) {
    union { float f; unsigned u; } v; v.f = f;
    unsigned r = v.u + 0x7FFF + ((v.u >> 16) & 1);
    return (u16)(r >> 16);
}

static __device__ __forceinline__ unsigned cvt_pk_bf16(float lo, float hi) {
    unsigned r;
    asm("v_cvt_pk_bf16_f32 %0, %1, %2" : "=v"(r) : "v"(lo), "v"(hi));
    return r;
}

static __device__ __forceinline__ void pswap2(unsigned &a, unsigned &b) {
#if defined(__has_builtin) && __has_builtin(__builtin_amdgcn_permlane32_swap)
    auto r = __builtin_amdgcn_permlane32_swap(a, b, false, false);
    a = r[0]; b = r[1];
#else
    asm volatile("v_permlane32_swap_b32 %0, %1" : "+v"(a), "+v"(b));
#endif
}

static __device__ __forceinline__ float xhalf_sum(float x) {
    unsigned a = __float_as_uint(x), b = a;
    pswap2(a, b);
    return __uint_as_float(a) + __uint_as_float(b);
}

static __device__ __forceinline__ float fexp2(float x) {
#if defined(__has_builtin) && __has_builtin(__builtin_amdgcn_exp2f)
    return __builtin_amdgcn_exp2f(x);
#else
    return exp2f(x);
#endif
}

#define GLOAD_LDS16(gptr, lptr) \
    __builtin_amdgcn_global_load_lds((const __attribute__((address_space(1))) void*)(gptr), \
                                     (__attribute__((address_space(3))) void*)(lptr), 16, 0, 0)

// ---------------- fused conversion kernel (one launch) ----------------
__global__ void cvt_all(const float* __restrict__ x, u16* __restrict__ xb,
                        const float* __restrict__ wq, u16* __restrict__ wqT,
                        const float* __restrict__ wo, u16* __restrict__ woT) {
    __shared__ float tile[32][33];
    const int bid = blockIdx.x;
    if (bid < 8192) {
        int i = (bid * 256 + threadIdx.x) * 4;
        f32x4 v = *(const f32x4*)(x + i);
        u16x4 o;
        o.x = f32_to_bf16(v.x); o.y = f32_to_bf16(v.y);
        o.z = f32_to_bf16(v.z); o.w = f32_to_bf16(v.w);
        *(u16x4*)(xb + i) = o;
    } else if (bid < 8192 + 3072) {
        const int b = bid - 8192;
        const int kb = b & 31, eb = (b >> 5) % 6, h = b / 192;
        const int xl = threadIdx.x & 31, y = threadIdx.x >> 5;
#pragma unroll
        for (int j = 0; j < 4; ++j) {
            int kl = y + j * 8;
            tile[kl][xl] = wq[((size_t)(h * 1024 + kb * 32 + kl)) * 192 + eb * 32 + xl];
        }
        __syncthreads();
#pragma unroll
        for (int j = 0; j < 4; ++j) {
            int el = y + j * 8;
            wqT[((size_t)(h * 192 + eb * 32 + el)) * 1024 + kb * 32 + xl] = f32_to_bf16(tile[xl][el]);
        }
    } else {
        const int b = bid - 8192 - 3072;
        const int kb = b & 31, nb = b >> 5;
        const int xl = threadIdx.x & 31, y = threadIdx.x >> 5;
#pragma unroll
        for (int j = 0; j < 4; ++j) {
            int kl = y + j * 8;
            tile[kl][xl] = wo[((size_t)(kb * 32 + kl)) * 1024 + nb * 32 + xl];
        }
        __syncthreads();
#pragma unroll
        for (int j = 0; j < 4; ++j) {
            int nl = y + j * 8;
            woT[((size_t)(nb * 32 + nl)) * 1024 + kb * 32 + xl] = f32_to_bf16(tile[xl][nl]);
        }
    }
}

// ---------------- GEMM: A[M][K] (bf16) x B^T[N][K] (bf16), K = 1024 -------
// Round-12 exact (16x16x32 MFMA; 32x32 variant measured -6 us in R14).

#define SWZ4(r) (((r) & 3) ^ (((r) >> 2) & 3))

template <int EPI>
__global__ __launch_bounds__(256, 3)
void gemm_bt(const u16* __restrict__ A, const u16* __restrict__ B,
             float* __restrict__ Cf, u16* __restrict__ Qb, u16* __restrict__ Kb,
             u16* __restrict__ Vt, int M, int N, int K) {
    __shared__ __align__(16) u16 lA[3 * 128 * 32];
    __shared__ __align__(16) u16 lB[3 * 128 * 32];

    const int t = threadIdx.x;
    const int lane = t & 63;
    const int wave = t >> 6;
    const int wr = wave >> 1, wc = wave & 1;
    const int l15 = lane & 15, g = lane >> 4;

    const int nwg = gridDim.x;
    const int cpx = nwg >> 3;
    const int orig = blockIdx.x;
    const int logical = (orig & 7) * cpx + (orig >> 3);

    const int nbx = N >> 7;
    const int bx = logical % nbx, by = logical / nbx;
    const int bm = by << 7, bn = bx << 7;

    f32x4 acc[4][4] = {};

    const int sr0 = t >> 2;
    const int ss  = t & 3;

    const u16* Abase = A + (size_t)bm * K;
    const u16* Bbase = B + (size_t)bn * K;

    int aoff[4], boff[4];
#pragma unroll
    for (int i = 0; i < 4; ++i) {
        int ra = wr * 64 + i * 16 + l15;
        aoff[i] = (ra * 4 + (g ^ SWZ4(ra))) * 8;
        int rb = wc * 64 + i * 16 + l15;
        boff[i] = (rb * 4 + (g ^ SWZ4(rb))) * 8;
    }

#define GSTAGE(bb, kt) do { \
    _Pragma("unroll") \
    for (int c = 0; c < 2; ++c) { \
        int r = sr0 + 64 * c; \
        int cl = ss ^ SWZ4(r); \
        GLOAD_LDS16(Abase + (size_t)r * K + (kt) + cl * 8, &lA[(bb) + (r * 4 + ss) * 8]); \
        GLOAD_LDS16(Bbase + (size_t)r * K + (kt) + cl * 8, &lB[(bb) + (r * 4 + ss) * 8]); \
    } } while (0)

#define GEMM_STEP(B0, B2, KT, DO_STAGE, DO_SYNC, WAIT4)                        \
  {                                                                            \
    if (DO_STAGE) GSTAGE((B2) * 4096, (KT));                                   \
    s16x8 a0 = *(const s16x8*)&lA[(B0) * 4096 + aoff[0]];                      \
    s16x8 a1 = *(const s16x8*)&lA[(B0) * 4096 + aoff[1]];                      \
    s16x8 a2 = *(const s16x8*)&lA[(B0) * 4096 + aoff[2]];                      \
    s16x8 a3 = *(const s16x8*)&lA[(B0) * 4096 + aoff[3]];                      \
    s16x8 b0 = *(const s16x8*)&lB[(B0) * 4096 + boff[0]];                      \
    s16x8 b1 = *(const s16x8*)&lB[(B0) * 4096 + boff[1]];                      \
    s16x8 b2 = *(const s16x8*)&lB[(B0) * 4096 + boff[2]];                      \
    s16x8 b3 = *(const s16x8*)&lB[(B0) * 4096 + boff[3]];                      \
    acc[0][0] = __builtin_amdgcn_mfma_f32_16x16x32_bf16(b0, a0, acc[0][0], 0, 0, 0); \
    acc[0][1] = __builtin_amdgcn_mfma_f32_16x16x32_bf16(b1, a0, acc[0][1], 0, 0, 0); \
    acc[0][2] = __builtin_amdgcn_mfma_f32_16x16x32_bf16(b2, a0, acc[0][2], 0, 0, 0); \
    acc[0][3] = __builtin_amdgcn_mfma_f32_16x16x32_bf16(b3, a0, acc[0][3], 0, 0, 0); \
    acc[1][0] = __builtin_amdgcn_mfma_f32_16x16x32_bf16(b0, a1, acc[1][0], 0, 0, 0); \
    acc[1][1] = __builtin_amdgcn_mfma_f32_16x16x32_bf16(b1, a1, acc[1][1], 0, 0, 0); \
    acc[1][2] = __builtin_amdgcn_mfma_f32_16x16x32_bf16(b2, a1, acc[1][2], 0, 0, 0); \
    acc[1][3] = __builtin_amdgcn_mfma_f32_16x16x32_bf16(b3, a1, acc[1][3], 0, 0, 0); \
    acc[2][0] = __builtin_amdgcn_mfma_f32_16x16x32_bf16(b0, a2, acc[2][0], 0, 0, 0); \
    acc[2][1] = __builtin_amdgcn_mfma_f32_16x16x32_bf16(b1, a2, acc[2][1], 0, 0, 0); \
    acc[2][2] = __builtin_amdgcn_mfma_f32_16x16x32_bf16(b2, a2, acc[2][2], 0, 0, 0); \
    acc[2][3] = __builtin_amdgcn_mfma_f32_16x16x32_bf16(b3, a2, acc[2][3], 0, 0, 0); \
    acc[3][0] = __builtin_amdgcn_mfma_f32_16x16x32_bf16(b0, a3, acc[3][0], 0, 0, 0); \
    acc[3][1] = __builtin_amdgcn_mfma_f32_16x16x32_bf16(b1, a3, acc[3][1], 0, 0, 0); \
    acc[3][2] = __builtin_amdgcn_mfma_f32_16x16x32_bf16(b2, a3, acc[3][2], 0, 0, 0); \
    acc[3][3] = __builtin_amdgcn_mfma_f32_16x16x32_bf16(b3, a3, acc[3][3], 0, 0, 0); \
    if (DO_SYNC) {                                                             \
      if (WAIT4) { asm volatile("s_waitcnt vmcnt(4)" ::: "memory"); }          \
      else       { asm volatile("s_waitcnt vmcnt(0)" ::: "memory"); }          \
      __builtin_amdgcn_s_barrier();                                            \
      __builtin_amdgcn_sched_barrier(0);                                       \
    }                                                                          \
  }

    GSTAGE(0, 0);
    GSTAGE(4096, 32);
    asm volatile("s_waitcnt vmcnt(4)" ::: "memory");
    __builtin_amdgcn_s_barrier();
    __builtin_amdgcn_sched_barrier(0);

#pragma unroll 1
    for (int tt = 0; tt < 30; tt += 3) {
        GEMM_STEP(0, 2, (tt + 2) << 5, true, true, true);
        GEMM_STEP(1, 0, (tt + 3) << 5, true, true, true);
        GEMM_STEP(2, 1, (tt + 4) << 5, true, true, true);
    }
    GEMM_STEP(0, 0, 0, false, true, false);
    GEMM_STEP(1, 0, 0, false, false, false);
#undef GEMM_STEP
#undef GSTAGE

    if constexpr (EPI == 0) {
#pragma unroll
        for (int i = 0; i < 4; ++i) {
            int m = bm + wr * 64 + i * 16 + l15;
#pragma unroll
            for (int j = 0; j < 4; ++j) {
                int n0 = bn + wc * 64 + j * 16 + g * 4;
                *(f32x4*)&Cf[(size_t)m * N + n0] = acc[i][j];
            }
        }
    } else {
        const float qscale = 0.022542110013890054f;   // log2(e)/64
#pragma unroll
        for (int j = 0; j < 4; ++j) {
            int n0 = bn + wc * 64 + j * 16 + g * 4;
            int h = n0 / 192;
            int e0 = n0 - h * 192;
#pragma unroll
            for (int i = 0; i < 4; ++i) {
                int m = bm + wr * 64 + i * 16 + l15;
                int bb = m >> 11, s = m & 2047;
                int bh = bb * 16 + h;
                if (e0 < 64) {
                    u16x4 q;
#pragma unroll
                    for (int r = 0; r < 4; ++r) q[r] = f32_to_bf16(acc[i][j][r] * qscale);
                    *(u16x4*)&Qb[((size_t)bh * 2048 + s) * 64 + e0] = q;
                } else if (e0 < 128) {
                    u16x4 kk;
#pragma unroll
                    for (int r = 0; r < 4; ++r) kk[r] = f32_to_bf16(acc[i][j][r]);
                    *(u16x4*)&Kb[((size_t)bh * 2048 + s) * 64 + (e0 - 64)] = kk;
                } else {
#pragma unroll
                    for (int r = 0; r < 4; ++r)
                        Vt[((size_t)bh * 64 + (e0 - 128 + r)) * 2048 + s] = f32_to_bf16(acc[i][j][r]);
                }
            }
        }
    }
}

// ---------------- attention helper: softmax + pack for one 32-key block ----

static __device__ __forceinline__ void soft_pack32(f32x16& p0, float& l,
                                                   s16x8& pv0, s16x8& pv1) {
    float rs0 = 0.f, rs1 = 0.f, rs2 = 0.f, rs3 = 0.f;
#pragma unroll
    for (int r = 0; r < 16; r += 4) {
        p0[r]     = fexp2(p0[r]);     rs0 += p0[r];
        p0[r + 1] = fexp2(p0[r + 1]); rs1 += p0[r + 1];
        p0[r + 2] = fexp2(p0[r + 2]); rs2 += p0[r + 2];
        p0[r + 3] = fexp2(p0[r + 3]); rs3 += p0[r + 3];
    }
    l += xhalf_sum((rs0 + rs1) + (rs2 + rs3));

    unsigned c0 = cvt_pk_bf16(p0[0],  p0[1]);
    unsigned c1 = cvt_pk_bf16(p0[2],  p0[3]);
    unsigned c2 = cvt_pk_bf16(p0[4],  p0[5]);
    unsigned c3 = cvt_pk_bf16(p0[6],  p0[7]);
    unsigned c4 = cvt_pk_bf16(p0[8],  p0[9]);
    unsigned c5 = cvt_pk_bf16(p0[10], p0[11]);
    unsigned c6 = cvt_pk_bf16(p0[12], p0[13]);
    unsigned c7 = cvt_pk_bf16(p0[14], p0[15]);
    pswap2(c0, c2); pswap2(c1, c3);
    pswap2(c4, c6); pswap2(c5, c7);
    union { unsigned u[8]; s16x8 v[2]; } pa;
    pa.u[0] = c0; pa.u[1] = c1; pa.u[2] = c2; pa.u[3] = c3;
    pa.u[4] = c4; pa.u[5] = c5; pa.u[6] = c6; pa.u[7] = c7;
    pv0 = pa.v[0]; pv1 = pa.v[1];
}

// ---------------- Flash attention: in-block KV-split, 8 waves/SIMD --------
// 1024 blocks x 512 threads. Waves 0-3: q-group qg=w, keys [0,1024);
// waves 4-7: same q-rows, keys [1024,2048). KVBLK=32 per stream, 2 LDS
// buffers per stream (32 KB total -> 4 blocks/CU = 32 waves/CU).
// Schedule per tile: compute(b) -> vmcnt(0) (pre-hidden: stage(t+1) had a
// full compute phase to land) -> barrier -> STAGE(b, t+2) into freed buffer.
// exp2-direct softmax (no max) => halves combine by plain addition at end.
__global__ __launch_bounds__(512, 8)
void attn32(const u16* __restrict__ Qb, const u16* __restrict__ Kb,
            const u16* __restrict__ Vt, u16* __restrict__ Zb) {
    __shared__ __align__(16) unsigned char smem[32768];
    __shared__ float lds_l[8][32];

    u16* lK = (u16*)smem;               // [st][buf][2048] u16 (16 KB)
    u16* lV = (u16*)(smem + 16384);     // [st][buf][2048] u16 (16 KB)
    float* scr = (float*)smem;          // epilogue overlay: [qg][r(32)][lane(64)]

    const int t = threadIdx.x;
    const int lane = t & 63;
    const int w = t >> 6;
    const int qg = w & 3, kh = w >> 2;
    const int l31 = lane & 31, hi = lane >> 5;
    const int r7 = l31 & 7;

    // bijective XCD swizzle: 1024 blocks -> 128 contiguous logical per XCD
    const int orig = blockIdx.x;
    const int logical = (orig & 7) * 128 + (orig >> 3);
    const int bh = logical >> 4;
    const int qt = logical & 15;
    const int q0 = qt * 128 + qg * 32;

    const u16* Kbh = Kb + ((size_t)bh * 2048 + kh * 1024) * 64;
    const u16* Vbh = Vt + (size_t)bh * 64 * 2048 + kh * 1024;

    u16* lKw = lK + kh * 4096;
    u16* lVw = lV + kh * 4096;

    const u16* Qp = Qb + ((size_t)bh * 2048 + q0 + l31) * 64 + hi * 8;
    const s16x8 qf0 = *(const s16x8*)(Qp);
    const s16x8 qf1 = *(const s16x8*)(Qp + 16);
    const s16x8 qf2 = *(const s16x8*)(Qp + 32);
    const s16x8 qf3 = *(const s16x8*)(Qp + 48);

    // hoisted LDS element offsets (verified in R13's refcheck-passing kernel)
    const int ka0 = l31 * 64 + (((0 + hi) ^ r7) << 3);
    const int ka1 = l31 * 64 + (((2 + hi) ^ r7) << 3);
    const int ka2 = l31 * 64 + (((4 + hi) ^ r7) << 3);
    const int ka3 = l31 * 64 + (((6 + hi) ^ r7) << 3);
    const int s3  = (l31 >> 1) & 3;
    const int va0 = l31 * 32 + (((0 + hi) ^ s3) << 3);
    const int va1 = l31 * 32 + (((2 + hi) ^ s3) << 3);

    f32x16 o0 = {}, o1 = {};
    float l = 0.f;

#define STAGE(bufe, tile) do { \
    int gr = (qg << 3) + (lane >> 3); \
    GLOAD_LDS16(Kbh + (size_t)(((tile) << 5) + gr) * 64 + (((lane & 7) ^ (lane >> 3)) << 3), \
                lKw + (bufe) * 2048 + (qg << 9) + lane * 8); \
    int vr = (qg << 4) + (lane >> 2); \
    GLOAD_LDS16(Vbh + (size_t)vr * 2048 + ((tile) << 5) + (((lane & 3) ^ ((lane >> 3) & 3)) << 3), \
                lVw + (bufe) * 2048 + (qg << 9) + lane * 8); \
} while (0)

#define ATTN_STEP(B, T2, DO_STAGE, DO_SYNC)                                          \
  {                                                                                  \
    f32x16 p0 = {};                                                                  \
    __builtin_amdgcn_s_setprio(1);                                                   \
    {                                                                                \
      s16x8 kf;                                                                      \
      kf = *(const s16x8*)&lKw[(B) * 2048 + ka0];                                    \
      p0 = __builtin_amdgcn_mfma_f32_32x32x16_bf16(kf, qf0, p0, 0, 0, 0);            \
      kf = *(const s16x8*)&lKw[(B) * 2048 + ka1];                                    \
      p0 = __builtin_amdgcn_mfma_f32_32x32x16_bf16(kf, qf1, p0, 0, 0, 0);            \
      kf = *(const s16x8*)&lKw[(B) * 2048 + ka2];                                    \
      p0 = __builtin_amdgcn_mfma_f32_32x32x16_bf16(kf, qf2, p0, 0, 0, 0);            \
      kf = *(const s16x8*)&lKw[(B) * 2048 + ka3];                                    \
      p0 = __builtin_amdgcn_mfma_f32_32x32x16_bf16(kf, qf3, p0, 0, 0, 0);            \
    }                                                                                \
    __builtin_amdgcn_s_setprio(0);                                                   \
    s16x8 pv0, pv1;                                                                  \
    soft_pack32(p0, l, pv0, pv1);                                                    \
    __builtin_amdgcn_s_setprio(1);                                                   \
    {                                                                                \
      s16x8 vf;                                                                      \
      vf = *(const s16x8*)&lVw[(B) * 2048 + va0];                                    \
      o0 = __builtin_amdgcn_mfma_f32_32x32x16_bf16(pv0, vf, o0, 0, 0, 0);            \
      vf = *(const s16x8*)&lVw[(B) * 2048 + va0 + 1024];                             \
      o1 = __builtin_amdgcn_mfma_f32_32x32x16_bf16(pv0, vf, o1, 0, 0, 0);            \
      vf = *(const s16x8*)&lVw[(B) * 2048 + va1];                                    \
      o0 = __builtin_amdgcn_mfma_f32_32x32x16_bf16(pv1, vf, o0, 0, 0, 0);            \
      vf = *(const s16x8*)&lVw[(B) * 2048 + va1 + 1024];                             \
      o1 = __builtin_amdgcn_mfma_f32_32x32x16_bf16(pv1, vf, o1, 0, 0, 0);            \
    }                                                                                \
    __builtin_amdgcn_s_setprio(0);                                                   \
    if (DO_SYNC) {                                                                   \
      asm volatile("s_waitcnt vmcnt(0)" ::: "memory");                               \
      __builtin_amdgcn_s_barrier();                                                  \
      __builtin_amdgcn_sched_barrier(0);                                             \
    }                                                                                \
    if (DO_STAGE) STAGE(B, T2);                                                      \
  }

    // prologue: stage tiles 0 (buf0) and 1 (buf1); wait tile 0 landed
    STAGE(0, 0);
    STAGE(1, 1);
    asm volatile("s_waitcnt vmcnt(2)" ::: "memory");
    __builtin_amdgcn_s_barrier();
    __builtin_amdgcn_sched_barrier(0);

    // 32 tiles of 32 keys; unroll 2 so buffer bases are literals
#pragma unroll 1
    for (int tt = 0; tt < 30; tt += 2) {
        ATTN_STEP(0, tt + 2, true, true);
        ATTN_STEP(1, tt + 3, true, true);
    }
    ATTN_STEP(0, 0, false, true);   // t=30 (waits stage(31))
    ATTN_STEP(1, 0, false, false);  // t=31
#undef ATTN_STEP
#undef STAGE

    // ---- combine the two KV halves (plain addition: no-max exp2 softmax) ----
    if (lane < 32) lds_l[w][l31] = l;
    __syncthreads();

    if (w >= 4) {
        float* sp = scr + (qg * 32) * 64 + lane;
#pragma unroll
        for (int r = 0; r < 16; ++r) {
            sp[r * 64]        = o0[r];
            sp[(16 + r) * 64] = o1[r];
        }
    }
    __syncthreads();

    if (w < 4) {
        const float* sp = scr + (qg * 32) * 64 + lane;
#pragma unroll
        for (int r = 0; r < 16; ++r) {
            o0[r] += sp[r * 64];
            o1[r] += sp[(16 + r) * 64];
        }
        const int b = bh >> 4, h = bh & 15;
#pragma unroll
        for (int r = 0; r < 16; ++r) {
            int qrow = (r & 3) + 8 * (r >> 2) + 4 * hi;
            float inv = 1.0f / (lds_l[w][qrow] + lds_l[w + 4][qrow]);
            size_t rowbase = ((size_t)(b * 2048 + q0 + qrow)) * 1024 + h * 64 + l31;
            Zb[rowbase]      = f32_to_bf16(o0[r] * inv);
            Zb[rowbase + 32] = f32_to_bf16(o1[r] * inv);
        }
    }
}

// ---------------- launch ----------------

extern "C" void kernel_launch(void* const* d_in, const int* in_sizes, int n_in,
                              void* d_out, int out_size, void* d_ws, size_t ws_size,
                              hipStream_t stream) {
    const float* x     = (const float*)d_in[0];
    const float* w_qkv = (const float*)d_in[1];
    const float* w_out = (const float*)d_in[2];
    float* out = (float*)d_out;

    char* ws = (char*)d_ws;
    u16* xb  = (u16*)ws; ws += (size_t)8192 * 1024 * 2;
    u16* wqT = (u16*)ws; ws += (size_t)3072 * 1024 * 2;
    u16* woT = (u16*)ws; ws += (size_t)1024 * 1024 * 2;
    u16* Qb  = (u16*)ws; ws += (size_t)64 * 2048 * 64 * 2;
    u16* Kb  = (u16*)ws; ws += (size_t)64 * 2048 * 64 * 2;
    u16* Vt  = (u16*)ws; ws += (size_t)64 * 2048 * 64 * 2;
    u16* Zb  = (u16*)ws; ws += (size_t)8192 * 1024 * 2;

    cvt_all<<<dim3(8192 + 3072 + 1024), dim3(256), 0, stream>>>(x, xb, w_qkv, wqT, w_out, woT);

    gemm_bt<1><<<dim3(64 * 24), dim3(256), 0, stream>>>(xb, wqT, nullptr, Qb, Kb, Vt,
                                                        8192, 3072, 1024);
    attn32<<<dim3(1024), dim3(512), 0, stream>>>(Qb, Kb, Vt, Zb);
    gemm_bt<0><<<dim3(64 * 8), dim3(256), 0, stream>>>(Zb, woT, out, nullptr, nullptr, nullptr,
                                                       8192, 1024, 1024);
}

// Round 16
// 183.213 us; speedup vs baseline: 2.0075x; 2.0075x over previous
//
#include <hip/hip_runtime.h>
#include <hip/hip_bf16.h>

typedef unsigned short u16;
typedef __attribute__((ext_vector_type(4))) float f32x4;
typedef __attribute__((ext_vector_type(16))) float f32x16;
typedef __attribute__((ext_vector_type(8))) short s16x8;
typedef __attribute__((ext_vector_type(4))) unsigned short u16x4;

static __device__ __forceinline__ u16 f32_to_bf16(float f) {
    union { float f; unsigned u; } v; v.f = f;
    unsigned r = v.u + 0x7FFF + ((v.u >> 16) & 1);
    return (u16)(r >> 16);
}

static __device__ __forceinline__ unsigned cvt_pk_bf16(float lo, float hi) {
    unsigned r;
    asm("v_cvt_pk_bf16_f32 %0, %1, %2" : "=v"(r) : "v"(lo), "v"(hi));
    return r;
}

static __device__ __forceinline__ void pswap2(unsigned &a, unsigned &b) {
#if defined(__has_builtin) && __has_builtin(__builtin_amdgcn_permlane32_swap)
    auto r = __builtin_amdgcn_permlane32_swap(a, b, false, false);
    a = r[0]; b = r[1];
#else
    asm volatile("v_permlane32_swap_b32 %0, %1" : "+v"(a), "+v"(b));
#endif
}

static __device__ __forceinline__ float xhalf_sum(float x) {
    unsigned a = __float_as_uint(x), b = a;
    pswap2(a, b);
    return __uint_as_float(a) + __uint_as_float(b);
}

static __device__ __forceinline__ float fexp2(float x) {
#if defined(__has_builtin) && __has_builtin(__builtin_amdgcn_exp2f)
    return __builtin_amdgcn_exp2f(x);
#else
    return exp2f(x);
#endif
}

#define GLOAD_LDS16(gptr, lptr) \
    __builtin_amdgcn_global_load_lds((const __attribute__((address_space(1))) void*)(gptr), \
                                     (__attribute__((address_space(3))) void*)(lptr), 16, 0, 0)

// ---------------- fused conversion kernel (one launch) ----------------
__global__ void cvt_all(const float* __restrict__ x, u16* __restrict__ xb,
                        const float* __restrict__ wq, u16* __restrict__ wqT,
                        const float* __restrict__ wo, u16* __restrict__ woT) {
    __shared__ float tile[32][33];
    const int bid = blockIdx.x;
    if (bid < 8192) {
        int i = (bid * 256 + threadIdx.x) * 4;
        f32x4 v = *(const f32x4*)(x + i);
        u16x4 o;
        o.x = f32_to_bf16(v.x); o.y = f32_to_bf16(v.y);
        o.z = f32_to_bf16(v.z); o.w = f32_to_bf16(v.w);
        *(u16x4*)(xb + i) = o;
    } else if (bid < 8192 + 3072) {
        const int b = bid - 8192;
        const int kb = b & 31, eb = (b >> 5) % 6, h = b / 192;
        const int xl = threadIdx.x & 31, y = threadIdx.x >> 5;
#pragma unroll
        for (int j = 0; j < 4; ++j) {
            int kl = y + j * 8;
            tile[kl][xl] = wq[((size_t)(h * 1024 + kb * 32 + kl)) * 192 + eb * 32 + xl];
        }
        __syncthreads();
#pragma unroll
        for (int j = 0; j < 4; ++j) {
            int el = y + j * 8;
            wqT[((size_t)(h * 192 + eb * 32 + el)) * 1024 + kb * 32 + xl] = f32_to_bf16(tile[xl][el]);
        }
    } else {
        const int b = bid - 8192 - 3072;
        const int kb = b & 31, nb = b >> 5;
        const int xl = threadIdx.x & 31, y = threadIdx.x >> 5;
#pragma unroll
        for (int j = 0; j < 4; ++j) {
            int kl = y + j * 8;
            tile[kl][xl] = wo[((size_t)(kb * 32 + kl)) * 1024 + nb * 32 + xl];
        }
        __syncthreads();
#pragma unroll
        for (int j = 0; j < 4; ++j) {
            int nl = y + j * 8;
            woT[((size_t)(nb * 32 + nl)) * 1024 + kb * 32 + xl] = f32_to_bf16(tile[xl][nl]);
        }
    }
}

// ---------------- GEMM: A[M][K] (bf16) x B^T[N][K] (bf16), K = 1024 -------
// 3-buffer counted-vmcnt pipeline, modulo-3 unrolled so LDS buffer bases are
// compile-time literals (addressing folds into ds_read offset immediates).
// LDS swizzle: slot = chunk ^ (r&3) ^ ((r>>2)&3) (phase-conflict-free).
// MFMA operands swapped (mfma(b,a)) so per-lane acc regs span N.
// EPI=1: Q pre-scaled by log2(e)/64 (attention runs in exp2 domain).

#define SWZ4(r) (((r) & 3) ^ (((r) >> 2) & 3))

template <int EPI>
__global__ __launch_bounds__(256, 3)
void gemm_bt(const u16* __restrict__ A, const u16* __restrict__ B,
             float* __restrict__ Cf, u16* __restrict__ Qb, u16* __restrict__ Kb,
             u16* __restrict__ Vt, int M, int N, int K) {
    __shared__ __align__(16) u16 lA[3 * 128 * 32];
    __shared__ __align__(16) u16 lB[3 * 128 * 32];

    const int t = threadIdx.x;
    const int lane = t & 63;
    const int wave = t >> 6;
    const int wr = wave >> 1, wc = wave & 1;
    const int l15 = lane & 15, g = lane >> 4;

    const int nwg = gridDim.x;
    const int cpx = nwg >> 3;
    const int orig = blockIdx.x;
    const int logical = (orig & 7) * cpx + (orig >> 3);

    const int nbx = N >> 7;
    const int bx = logical % nbx, by = logical / nbx;
    const int bm = by << 7, bn = bx << 7;

    f32x4 acc[4][4] = {};

    const int sr0 = t >> 2;
    const int ss  = t & 3;

    const u16* Abase = A + (size_t)bm * K;
    const u16* Bbase = B + (size_t)bn * K;

    int aoff[4], boff[4];
#pragma unroll
    for (int i = 0; i < 4; ++i) {
        int ra = wr * 64 + i * 16 + l15;
        aoff[i] = (ra * 4 + (g ^ SWZ4(ra))) * 8;
        int rb = wc * 64 + i * 16 + l15;
        boff[i] = (rb * 4 + (g ^ SWZ4(rb))) * 8;
    }

#define GSTAGE(bb, kt) do { \
    _Pragma("unroll") \
    for (int c = 0; c < 2; ++c) { \
        int r = sr0 + 64 * c; \
        int cl = ss ^ SWZ4(r); \
        GLOAD_LDS16(Abase + (size_t)r * K + (kt) + cl * 8, &lA[(bb) + (r * 4 + ss) * 8]); \
        GLOAD_LDS16(Bbase + (size_t)r * K + (kt) + cl * 8, &lB[(bb) + (r * 4 + ss) * 8]); \
    } } while (0)

#define GEMM_STEP(B0, B2, KT, DO_STAGE, DO_SYNC, WAIT4)                        \
  {                                                                            \
    if (DO_STAGE) GSTAGE((B2) * 4096, (KT));                                   \
    s16x8 a0 = *(const s16x8*)&lA[(B0) * 4096 + aoff[0]];                      \
    s16x8 a1 = *(const s16x8*)&lA[(B0) * 4096 + aoff[1]];                      \
    s16x8 a2 = *(const s16x8*)&lA[(B0) * 4096 + aoff[2]];                      \
    s16x8 a3 = *(const s16x8*)&lA[(B0) * 4096 + aoff[3]];                      \
    s16x8 b0 = *(const s16x8*)&lB[(B0) * 4096 + boff[0]];                      \
    s16x8 b1 = *(const s16x8*)&lB[(B0) * 4096 + boff[1]];                      \
    s16x8 b2 = *(const s16x8*)&lB[(B0) * 4096 + boff[2]];                      \
    s16x8 b3 = *(const s16x8*)&lB[(B0) * 4096 + boff[3]];                      \
    acc[0][0] = __builtin_amdgcn_mfma_f32_16x16x32_bf16(b0, a0, acc[0][0], 0, 0, 0); \
    acc[0][1] = __builtin_amdgcn_mfma_f32_16x16x32_bf16(b1, a0, acc[0][1], 0, 0, 0); \
    acc[0][2] = __builtin_amdgcn_mfma_f32_16x16x32_bf16(b2, a0, acc[0][2], 0, 0, 0); \
    acc[0][3] = __builtin_amdgcn_mfma_f32_16x16x32_bf16(b3, a0, acc[0][3], 0, 0, 0); \
    acc[1][0] = __builtin_amdgcn_mfma_f32_16x16x32_bf16(b0, a1, acc[1][0], 0, 0, 0); \
    acc[1][1] = __builtin_amdgcn_mfma_f32_16x16x32_bf16(b1, a1, acc[1][1], 0, 0, 0); \
    acc[1][2] = __builtin_amdgcn_mfma_f32_16x16x32_bf16(b2, a1, acc[1][2], 0, 0, 0); \
    acc[1][3] = __builtin_amdgcn_mfma_f32_16x16x32_bf16(b3, a1, acc[1][3], 0, 0, 0); \
    acc[2][0] = __builtin_amdgcn_mfma_f32_16x16x32_bf16(b0, a2, acc[2][0], 0, 0, 0); \
    acc[2][1] = __builtin_amdgcn_mfma_f32_16x16x32_bf16(b1, a2, acc[2][1], 0, 0, 0); \
    acc[2][2] = __builtin_amdgcn_mfma_f32_16x16x32_bf16(b2, a2, acc[2][2], 0, 0, 0); \
    acc[2][3] = __builtin_amdgcn_mfma_f32_16x16x32_bf16(b3, a2, acc[2][3], 0, 0, 0); \
    acc[3][0] = __builtin_amdgcn_mfma_f32_16x16x32_bf16(b0, a3, acc[3][0], 0, 0, 0); \
    acc[3][1] = __builtin_amdgcn_mfma_f32_16x16x32_bf16(b1, a3, acc[3][1], 0, 0, 0); \
    acc[3][2] = __builtin_amdgcn_mfma_f32_16x16x32_bf16(b2, a3, acc[3][2], 0, 0, 0); \
    acc[3][3] = __builtin_amdgcn_mfma_f32_16x16x32_bf16(b3, a3, acc[3][3], 0, 0, 0); \
    if (DO_SYNC) {                                                             \
      if (WAIT4) { asm volatile("s_waitcnt vmcnt(4)" ::: "memory"); }          \
      else       { asm volatile("s_waitcnt vmcnt(0)" ::: "memory"); }          \
      __builtin_amdgcn_s_barrier();                                            \
      __builtin_amdgcn_sched_barrier(0);                                       \
    }                                                                          \
  }

    GSTAGE(0, 0);
    GSTAGE(4096, 32);
    asm volatile("s_waitcnt vmcnt(4)" ::: "memory");
    __builtin_amdgcn_s_barrier();
    __builtin_amdgcn_sched_barrier(0);

#pragma unroll 1
    for (int tt = 0; tt < 30; tt += 3) {
        GEMM_STEP(0, 2, (tt + 2) << 5, true, true, true);
        GEMM_STEP(1, 0, (tt + 3) << 5, true, true, true);
        GEMM_STEP(2, 1, (tt + 4) << 5, true, true, true);
    }
    GEMM_STEP(0, 0, 0, false, true, false);   // ti=30: drain + barrier
    GEMM_STEP(1, 0, 0, false, false, false);  // ti=31
#undef GEMM_STEP
#undef GSTAGE

    if constexpr (EPI == 0) {
#pragma unroll
        for (int i = 0; i < 4; ++i) {
            int m = bm + wr * 64 + i * 16 + l15;
#pragma unroll
            for (int j = 0; j < 4; ++j) {
                int n0 = bn + wc * 64 + j * 16 + g * 4;
                *(f32x4*)&Cf[(size_t)m * N + n0] = acc[i][j];
            }
        }
    } else {
        const float qscale = 0.022542110013890054f;   // log2(e)/64
#pragma unroll
        for (int j = 0; j < 4; ++j) {
            int n0 = bn + wc * 64 + j * 16 + g * 4;
            int h = n0 / 192;
            int e0 = n0 - h * 192;
#pragma unroll
            for (int i = 0; i < 4; ++i) {
                int m = bm + wr * 64 + i * 16 + l15;
                int bb = m >> 11, s = m & 2047;
                int bh = bb * 16 + h;
                if (e0 < 64) {
                    u16x4 q;
#pragma unroll
                    for (int r = 0; r < 4; ++r) q[r] = f32_to_bf16(acc[i][j][r] * qscale);
                    *(u16x4*)&Qb[((size_t)bh * 2048 + s) * 64 + e0] = q;
                } else if (e0 < 128) {
                    u16x4 kk;
#pragma unroll
                    for (int r = 0; r < 4; ++r) kk[r] = f32_to_bf16(acc[i][j][r]);
                    *(u16x4*)&Kb[((size_t)bh * 2048 + s) * 64 + (e0 - 64)] = kk;
                } else {
#pragma unroll
                    for (int r = 0; r < 4; ++r)
                        Vt[((size_t)bh * 64 + (e0 - 128 + r)) * 2048 + s] = f32_to_bf16(acc[i][j][r]);
                }
            }
        }
    }
}

// ---------------- attention helpers ----------------

static __device__ __forceinline__ void soft_pack(f32x16 p0, f32x16 p1, float& l,
                                                 s16x8& pv0, s16x8& pv1,
                                                 s16x8& pv2, s16x8& pv3) {
    float rs0 = 0.f, rs1 = 0.f, rs2 = 0.f, rs3 = 0.f;
#pragma unroll
    for (int r = 0; r < 16; r += 4) {
        p0[r]     = fexp2(p0[r]);     rs0 += p0[r];
        p0[r + 1] = fexp2(p0[r + 1]); rs1 += p0[r + 1];
        p0[r + 2] = fexp2(p0[r + 2]); rs2 += p0[r + 2];
        p0[r + 3] = fexp2(p0[r + 3]); rs3 += p0[r + 3];
        p1[r]     = fexp2(p1[r]);     rs0 += p1[r];
        p1[r + 1] = fexp2(p1[r + 1]); rs1 += p1[r + 1];
        p1[r + 2] = fexp2(p1[r + 2]); rs2 += p1[r + 2];
        p1[r + 3] = fexp2(p1[r + 3]); rs3 += p1[r + 3];
    }
    l += xhalf_sum((rs0 + rs1) + (rs2 + rs3));

    {
        unsigned c0 = cvt_pk_bf16(p0[0],  p0[1]);
        unsigned c1 = cvt_pk_bf16(p0[2],  p0[3]);
        unsigned c2 = cvt_pk_bf16(p0[4],  p0[5]);
        unsigned c3 = cvt_pk_bf16(p0[6],  p0[7]);
        unsigned c4 = cvt_pk_bf16(p0[8],  p0[9]);
        unsigned c5 = cvt_pk_bf16(p0[10], p0[11]);
        unsigned c6 = cvt_pk_bf16(p0[12], p0[13]);
        unsigned c7 = cvt_pk_bf16(p0[14], p0[15]);
        pswap2(c0, c2); pswap2(c1, c3);
        pswap2(c4, c6); pswap2(c5, c7);
        union { unsigned u[8]; s16x8 v[2]; } pa;
        pa.u[0] = c0; pa.u[1] = c1; pa.u[2] = c2; pa.u[3] = c3;
        pa.u[4] = c4; pa.u[5] = c5; pa.u[6] = c6; pa.u[7] = c7;
        pv0 = pa.v[0]; pv1 = pa.v[1];
    }
    {
        unsigned c0 = cvt_pk_bf16(p1[0],  p1[1]);
        unsigned c1 = cvt_pk_bf16(p1[2],  p1[3]);
        unsigned c2 = cvt_pk_bf16(p1[4],  p1[5]);
        unsigned c3 = cvt_pk_bf16(p1[6],  p1[7]);
        unsigned c4 = cvt_pk_bf16(p1[8],  p1[9]);
        unsigned c5 = cvt_pk_bf16(p1[10], p1[11]);
        unsigned c6 = cvt_pk_bf16(p1[12], p1[13]);
        unsigned c7 = cvt_pk_bf16(p1[14], p1[15]);
        pswap2(c0, c2); pswap2(c1, c3);
        pswap2(c4, c6); pswap2(c5, c7);
        union { unsigned u[8]; s16x8 v[2]; } pa;
        pa.u[0] = c0; pa.u[1] = c1; pa.u[2] = c2; pa.u[3] = c3;
        pa.u[4] = c4; pa.u[5] = c5; pa.u[6] = c6; pa.u[7] = c7;
        pv2 = pa.v[0]; pv3 = pa.v[1];
    }
}

// ---------------- Flash attention: 8-wave, 3-buffer counted-vmcnt ----------
// Round-12 exact (best measured attn config, 80.5 us).
__global__ __launch_bounds__(512, 4)
void attn32(const u16* __restrict__ Qb, const u16* __restrict__ Kb,
            const u16* __restrict__ Vt, u16* __restrict__ Zb) {
    __shared__ __align__(16) u16 lK[3 * 64 * 64];
    __shared__ __align__(16) u16 lV[3 * 64 * 64];
    __shared__ float lds_l[8][32];

    const int t = threadIdx.x;
    const int lane = t & 63;
    const int w = t >> 6;
    const int l31 = lane & 31, hi = lane >> 5;
    const int r7 = l31 & 7;

    const int orig = blockIdx.x;
    const int logical = (orig & 7) * 64 + (orig >> 3);
    const int bh = logical >> 3;
    const int qt = logical & 7;
    const int q0 = qt * 256 + w * 32;

    const u16* Kbh = Kb + (size_t)bh * 2048 * 64;
    const u16* Vbh = Vt + (size_t)bh * 64 * 2048;

    const int lr = lane >> 3;
    const int lc = (lane & 7) ^ lr;

    const u16* Qp = Qb + ((size_t)bh * 2048 + q0 + l31) * 64 + hi * 8;
    const s16x8 qf0 = *(const s16x8*)(Qp);
    const s16x8 qf1 = *(const s16x8*)(Qp + 16);
    const s16x8 qf2 = *(const s16x8*)(Qp + 32);
    const s16x8 qf3 = *(const s16x8*)(Qp + 48);

    const int ka0 = l31 * 64 + (((0 + hi) ^ r7) << 3);
    const int ka1 = l31 * 64 + (((2 + hi) ^ r7) << 3);
    const int ka2 = l31 * 64 + (((4 + hi) ^ r7) << 3);
    const int ka3 = l31 * 64 + (((6 + hi) ^ r7) << 3);

    f32x16 o0 = {}, o1 = {};
    float l = 0.f;

#define STAGE(bb, kvn) do { \
    int gr = w * 8 + lr; \
    GLOAD_LDS16(Kbh + (size_t)((kvn) + gr) * 64 + lc * 8, \
                &lK[(bb) + w * 512 + lane * 8]); \
    GLOAD_LDS16(Vbh + (size_t)gr * 2048 + (kvn) + lc * 8, \
                &lV[(bb) + w * 512 + lane * 8]); \
    } while (0)

#define ATTN_STEP(B0, B2, KVN, DO_STAGE, DO_SYNC, WAIT2)                             \
  {                                                                                  \
    if (DO_STAGE) STAGE((B2) * 4096, (KVN));                                         \
    f32x16 p0 = {}, p1 = {};                                                         \
    __builtin_amdgcn_s_setprio(1);                                                   \
    {                                                                                \
      s16x8 kf;                                                                      \
      kf = *(const s16x8*)&lK[(B0) * 4096 + ka0];                                    \
      p0 = __builtin_amdgcn_mfma_f32_32x32x16_bf16(kf, qf0, p0, 0, 0, 0);            \
      kf = *(const s16x8*)&lK[(B0) * 4096 + ka0 + 2048];                             \
      p1 = __builtin_amdgcn_mfma_f32_32x32x16_bf16(kf, qf0, p1, 0, 0, 0);            \
      kf = *(const s16x8*)&lK[(B0) * 4096 + ka1];                                    \
      p0 = __builtin_amdgcn_mfma_f32_32x32x16_bf16(kf, qf1, p0, 0, 0, 0);            \
      kf = *(const s16x8*)&lK[(B0) * 4096 + ka1 + 2048];                             \
      p1 = __builtin_amdgcn_mfma_f32_32x32x16_bf16(kf, qf1, p1, 0, 0, 0);            \
      kf = *(const s16x8*)&lK[(B0) * 4096 + ka2];                                    \
      p0 = __builtin_amdgcn_mfma_f32_32x32x16_bf16(kf, qf2, p0, 0, 0, 0);            \
      kf = *(const s16x8*)&lK[(B0) * 4096 + ka2 + 2048];                             \
      p1 = __builtin_amdgcn_mfma_f32_32x32x16_bf16(kf, qf2, p1, 0, 0, 0);            \
      kf = *(const s16x8*)&lK[(B0) * 4096 + ka3];                                    \
      p0 = __builtin_amdgcn_mfma_f32_32x32x16_bf16(kf, qf3, p0, 0, 0, 0);            \
      kf = *(const s16x8*)&lK[(B0) * 4096 + ka3 + 2048];                             \
      p1 = __builtin_amdgcn_mfma_f32_32x32x16_bf16(kf, qf3, p1, 0, 0, 0);            \
    }                                                                                \
    __builtin_amdgcn_s_setprio(0);                                                   \
    s16x8 pv0, pv1, pv2, pv3;                                                        \
    soft_pack(p0, p1, l, pv0, pv1, pv2, pv3);                                        \
    __builtin_amdgcn_s_setprio(1);                                                   \
    {                                                                                \
      s16x8 vf;                                                                      \
      vf = *(const s16x8*)&lV[(B0) * 4096 + ka0];                                    \
      o0 = __builtin_amdgcn_mfma_f32_32x32x16_bf16(pv0, vf, o0, 0, 0, 0);            \
      vf = *(const s16x8*)&lV[(B0) * 4096 + ka0 + 2048];                             \
      o1 = __builtin_amdgcn_mfma_f32_32x32x16_bf16(pv0, vf, o1, 0, 0, 0);            \
      vf = *(const s16x8*)&lV[(B0) * 4096 + ka1];                                    \
      o0 = __builtin_amdgcn_mfma_f32_32x32x16_bf16(pv1, vf, o0, 0, 0, 0);            \
      vf = *(const s16x8*)&lV[(B0) * 4096 + ka1 + 2048];                             \
      o1 = __builtin_amdgcn_mfma_f32_32x32x16_bf16(pv1, vf, o1, 0, 0, 0);            \
      vf = *(const s16x8*)&lV[(B0) * 4096 + ka2];                                    \
      o0 = __builtin_amdgcn_mfma_f32_32x32x16_bf16(pv2, vf, o0, 0, 0, 0);            \
      vf = *(const s16x8*)&lV[(B0) * 4096 + ka2 + 2048];                             \
      o1 = __builtin_amdgcn_mfma_f32_32x32x16_bf16(pv2, vf, o1, 0, 0, 0);            \
      vf = *(const s16x8*)&lV[(B0) * 4096 + ka3];                                    \
      o0 = __builtin_amdgcn_mfma_f32_32x32x16_bf16(pv3, vf, o0, 0, 0, 0);            \
      vf = *(const s16x8*)&lV[(B0) * 4096 + ka3 + 2048];                             \
      o1 = __builtin_amdgcn_mfma_f32_32x32x16_bf16(pv3, vf, o1, 0, 0, 0);            \
    }                                                                                \
    __builtin_amdgcn_s_setprio(0);                                                   \
    if (DO_SYNC) {                                                                   \
      if (WAIT2) { asm volatile("s_waitcnt vmcnt(2)" ::: "memory"); }                \
      else       { asm volatile("s_waitcnt vmcnt(0)" ::: "memory"); }                \
      __builtin_amdgcn_s_barrier();                                                  \
      __builtin_amdgcn_sched_barrier(0);                                             \
    }                                                                                \
  }

    STAGE(0, 0);
    STAGE(4096, 64);
    asm volatile("s_waitcnt vmcnt(2)" ::: "memory");
    __builtin_amdgcn_s_barrier();
    __builtin_amdgcn_sched_barrier(0);

#pragma unroll 1
    for (int tt = 0; tt < 30; tt += 3) {
        ATTN_STEP(0, 2, (tt + 2) << 6, true, true, true);
        ATTN_STEP(1, 0, (tt + 3) << 6, true, true, true);
        ATTN_STEP(2, 1, (tt + 4) << 6, true, true, true);
    }
    ATTN_STEP(0, 0, 0, false, true, false);   // ti=30: drain + barrier
    ATTN_STEP(1, 0, 0, false, false, false);  // ti=31
#undef ATTN_STEP
#undef STAGE

    if (lane < 32) lds_l[w][l31] = l;
    __syncthreads();

    const int b = bh >> 4, h = bh & 15;
#pragma unroll
    for (int r = 0; r < 16; ++r) {
        int qrow = (r & 3) + 8 * (r >> 2) + 4 * hi;
        float inv = 1.0f / lds_l[w][qrow];
        size_t rowbase = ((size_t)(b * 2048 + q0 + qrow)) * 1024 + h * 64 + l31;
        Zb[rowbase]      = f32_to_bf16(o0[r] * inv);
        Zb[rowbase + 32] = f32_to_bf16(o1[r] * inv);
    }
}

// ---------------- launch ----------------

extern "C" void kernel_launch(void* const* d_in, const int* in_sizes, int n_in,
                              void* d_out, int out_size, void* d_ws, size_t ws_size,
                              hipStream_t stream) {
    const float* x     = (const float*)d_in[0];
    const float* w_qkv = (const float*)d_in[1];
    const float* w_out = (const float*)d_in[2];
    float* out = (float*)d_out;

    char* ws = (char*)d_ws;
    u16* xb  = (u16*)ws; ws += (size_t)8192 * 1024 * 2;
    u16* wqT = (u16*)ws; ws += (size_t)3072 * 1024 * 2;
    u16* woT = (u16*)ws; ws += (size_t)1024 * 1024 * 2;
    u16* Qb  = (u16*)ws; ws += (size_t)64 * 2048 * 64 * 2;
    u16* Kb  = (u16*)ws; ws += (size_t)64 * 2048 * 64 * 2;
    u16* Vt  = (u16*)ws; ws += (size_t)64 * 2048 * 64 * 2;
    u16* Zb  = (u16*)ws; ws += (size_t)8192 * 1024 * 2;

    cvt_all<<<dim3(8192 + 3072 + 1024), dim3(256), 0, stream>>>(x, xb, w_qkv, wqT, w_out, woT);

    gemm_bt<1><<<dim3(64 * 24), dim3(256), 0, stream>>>(xb, wqT, nullptr, Qb, Kb, Vt,
                                                        8192, 3072, 1024);
    attn32<<<dim3(512), dim3(512), 0, stream>>>(Qb, Kb, Vt, Zb);
    gemm_bt<0><<<dim3(64 * 8), dim3(256), 0, stream>>>(Zb, woT, out, nullptr, nullptr, nullptr,
                                                       8192, 1024, 1024);
}